// Round 8
// baseline (433.914 us; speedup 1.0000x reference)
//
#include <hip/hip_runtime.h>
#include <hip/hip_fp16.h>
#include <math.h>

typedef _Float16 f16;
typedef _Float16 f16x4 __attribute__((ext_vector_type(4)));
typedef _Float16 f16x8 __attribute__((ext_vector_type(8)));
typedef float f32x4 __attribute__((ext_vector_type(4)));

#define GLOAD_LDS16(g, l)                                                                  \
    __builtin_amdgcn_global_load_lds((const __attribute__((address_space(1))) void*)(g),   \
                                     (__attribute__((address_space(3))) void*)(l), 16, 0, 0)

// Three-source f32 -> f16 cast with independent destinations, blockIdx.z selects.
__global__ __launch_bounds__(256) void cast3_kernel(const float* __restrict__ s0,
                                                    const float* __restrict__ s1,
                                                    const float* __restrict__ s2,
                                                    f16* d0, f16* d1, f16* d2, int n4each)
{
    const int z = blockIdx.z;
    const float* src = (z == 0) ? s0 : (z == 1) ? s1 : s2;
    f16* d = (z == 0) ? d0 : (z == 1) ? d1 : d2;
    const int stride = gridDim.x * blockDim.x;
    for (int i = blockIdx.x * blockDim.x + threadIdx.x; i < n4each; i += stride) {
        float4 v = *(const float4*)(src + (long long)i * 4);
        *(f16x4*)(d + (long long)i * 4) = (f16x4){(f16)v.x, (f16)v.y, (f16)v.z, (f16)v.w};
    }
}

// ============================================================================
// 256x256 tile NT GEMM, BK=64, 512 threads (8 waves 2Mx4N), 128 KiB LDS dbuf.
// m201-style 4-phase-per-K-tile schedule: per phase {ds_read quadrant; barrier;
// setprio(1); 16 MFMA; setprio(0); barrier} so waves stagger LDS reads vs MFMA.
// T2 both-sides swizzle (linear LDS dest + inverse-swizzled global src +
// swizzled ds_read).  Staging: all 8 gload_lds at tile start -> 4 phases
// (~1400 cyc) of latency cover; tile-boundary vmcnt(0) is a non-stall wait.
// C[M,N] = A[M,K](f16) * B[N,K](f16)^T.  M,N % 256 == 0, K % 128 == 0.
// Grid: dim3(nwg, 1, nz), nwg % 8 == 0; gx = N/256.
// ============================================================================
template <int OUTF16>
__global__ __launch_bounds__(512, 1) void gemm_nt_256(
    const f16* __restrict__ Ab, const f16* __restrict__ Bb, void* __restrict__ Cb,
    int K, int lda, int ldb, int ldc,
    long long sA, long long sB, long long sC, int gx)
{
    // [buf][half][128 rows][64 k] f16, linear (global_load_lds writes linearly)
    __shared__ __align__(16) f16 As[2][2][128 * 64];
    __shared__ __align__(16) f16 Bs[2][2][128 * 64];

    // XCD-aware bijective swizzle (nwg % 8 == 0).
    const int nwg = gridDim.x;
    const int swz = (blockIdx.x & 7) * (nwg >> 3) + (blockIdx.x >> 3);
    const int bx = swz % gx, by = swz / gx;

    const int z = blockIdx.z;
    const char* pA = (const char*)(Ab + z * sA + (long long)by * 256 * lda);
    const char* pB = (const char*)(Bb + z * sB + (long long)bx * 256 * ldb);
    const long long lda2 = (long long)lda * 2, ldb2 = (long long)ldb * 2;

    const int tid = threadIdx.x;
    const int w = tid >> 6, l = tid & 63;
    const int wr = w >> 2, wc = w & 3;          // 2 x 4 wave grid

    // --- staging geometry: per (half h, j), thread covers 16B at linear
    // offset (j*512+tid)*16 of the [128][64] half-tile.  row = that>>7.
    // T2: LDS stays linear; global col is inverse-swizzled (XOR involution).
    int rs[2], cs[2];
    rs[0] = tid >> 3;
    rs[1] = (512 + tid) >> 3;
    const int cb = (tid & 7) * 16;
    cs[0] = cb ^ ((rs[0] & 7) << 4);
    cs[1] = cb ^ ((rs[1] & 7) << 4);

#define STAGE_FULL(buf, kt)                                                               \
    do {                                                                                  \
        const long long kb_ = (long long)(kt) * 128;                                      \
        _Pragma("unroll")                                                                 \
        for (int h_ = 0; h_ < 2; h_++) {                                                  \
            _Pragma("unroll")                                                             \
            for (int j_ = 0; j_ < 2; j_++) {                                              \
                GLOAD_LDS16(pA + (long long)(h_ * 128 + rs[j_]) * lda2 + kb_ + cs[j_],    \
                            &As[buf][h_][j_ * 4096 + w * 512]);                           \
                GLOAD_LDS16(pB + (long long)(h_ * 128 + rs[j_]) * ldb2 + kb_ + cs[j_],    \
                            &Bs[buf][h_][j_ * 4096 + w * 512]);                           \
            }                                                                             \
        }                                                                                 \
    } while (0)

    // swizzled frag read: row256 in [0,256), cbyte in [0,128)
#define FRAG(arr, buf, row256, cbyte)                                                     \
    (*(const f16x8*)((const char*)&arr[buf][0][0] + (((row256) >> 7) * 16384) +           \
                     (((row256) & 127) * 128) + ((cbyte) ^ (((row256) & 7) << 4))))

    f32x4 acc[8][4];
#pragma unroll
    for (int i = 0; i < 8; i++)
#pragma unroll
        for (int j = 0; j < 4; j++) acc[i][j] = (f32x4){0.f, 0.f, 0.f, 0.f};

    const int lr = l & 15;          // frag row/col within 16
    const int lkb = (l >> 4) * 16;  // frag k sub-offset in bytes

    const int nt = K >> 6;
    STAGE_FULL(0, 0);
    asm volatile("s_waitcnt vmcnt(0)" ::: "memory");
    __builtin_amdgcn_s_barrier();
    __builtin_amdgcn_sched_barrier(0);

    for (int t = 0; t < nt; ++t) {
        const int buf = t & 1;
        if (t + 1 < nt) STAGE_FULL(buf ^ 1, t + 1);   // 8 loads, ~4 phases of cover

        f16x8 bf[4][2];
#pragma unroll
        for (int p = 0; p < 4; p++) {
            // ds_read for this phase (issued pre-barrier; latency hides under wait)
            if (p == 0) {
#pragma unroll
                for (int fc = 0; fc < 4; fc++)
#pragma unroll
                    for (int ks = 0; ks < 2; ks++)
                        bf[fc][ks] = FRAG(Bs, buf, wc * 64 + fc * 16 + lr, ks * 64 + lkb);
            }
            f16x8 af[2][2];
#pragma unroll
            for (int fr = 0; fr < 2; fr++)
#pragma unroll
                for (int ks = 0; ks < 2; ks++)
                    af[fr][ks] = FRAG(As, buf, wr * 128 + p * 32 + fr * 16 + lr, ks * 64 + lkb);

            __builtin_amdgcn_s_barrier();            // stagger point
            __builtin_amdgcn_sched_barrier(0);

            __builtin_amdgcn_s_setprio(1);
#pragma unroll
            for (int fr = 0; fr < 2; fr++)
#pragma unroll
                for (int fc = 0; fc < 4; fc++)
#pragma unroll
                    for (int ks = 0; ks < 2; ks++)
                        acc[p * 2 + fr][fc] = __builtin_amdgcn_mfma_f32_16x16x32_f16(
                            af[fr][ks], bf[fc][ks], acc[p * 2 + fr][fc], 0, 0, 0);
            __builtin_amdgcn_s_setprio(0);

            if (p == 3) {
                // publish tile t+1 (its 8 loads were issued a full tile ago);
                // also the only outstanding VMEM, so this is a counted wait.
                asm volatile("s_waitcnt vmcnt(0)" ::: "memory");
            }
            __builtin_amdgcn_s_barrier();            // phase end
            __builtin_amdgcn_sched_barrier(0);
        }
    }
#undef STAGE_FULL
#undef FRAG

    // C/D 16x16 layout: col = lane&15, row = (lane>>4)*4 + i  (HW-verified)
    const int row_l = (l >> 4) * 4;
    const long long gr0 = (long long)by * 256 + wr * 128;
    const int gc0 = bx * 256 + wc * 64;
    if (OUTF16) {
        f16* C = (f16*)Cb + z * sC;
#pragma unroll
        for (int fq = 0; fq < 8; fq++)
#pragma unroll
            for (int fc = 0; fc < 4; fc++)
#pragma unroll
                for (int i = 0; i < 4; i++)
                    C[(gr0 + fq * 16 + row_l + i) * ldc + gc0 + fc * 16 + lr] = (f16)acc[fq][fc][i];
    } else {
        float* C = (float*)Cb + z * sC;
#pragma unroll
        for (int fq = 0; fq < 8; fq++)
#pragma unroll
            for (int fc = 0; fc < 4; fc++)
#pragma unroll
                for (int i = 0; i < 4; i++)
                    C[(gr0 + fq * 16 + row_l + i) * ldc + gc0 + fc * 16 + lr] = acc[fq][fc][i];
    }
}

// vT[b][o][s] = v[b][s][o], 64x64 LDS tiles.
__global__ __launch_bounds__(256) void transpose_v_kernel(const f16* __restrict__ v, f16* __restrict__ vT)
{
    __shared__ f16 tile[64][72];
    const int b = blockIdx.z;
    const int s0 = blockIdx.x * 64, o0 = blockIdx.y * 64;
    const int t = threadIdx.x;
    const int r = t >> 2, c = (t & 3) * 16;
    const f16* src = v + ((long long)b * 2048 + s0) * 1024 + o0;
    *(f16x8*)&tile[r][c]     = *(const f16x8*)(src + (long long)r * 1024 + c);
    *(f16x8*)&tile[r][c + 8] = *(const f16x8*)(src + (long long)r * 1024 + c + 8);
    __syncthreads();
    f16* dst = vT + ((long long)b * 1024 + o0) * 2048 + s0;
    f16 buf[16];
#pragma unroll
    for (int j = 0; j < 16; j++) buf[j] = tile[c + j][r];
    *(f16x8*)(dst + (long long)r * 2048 + c)     = *(f16x8*)&buf[0];
    *(f16x8*)(dst + (long long)r * 2048 + c + 8) = *(f16x8*)&buf[8];
}

__device__ __forceinline__ float wred_max(float v) {
#pragma unroll
    for (int o = 32; o > 0; o >>= 1) v = fmaxf(v, __shfl_xor(v, o));
    return v;
}
__device__ __forceinline__ float wred_sum(float v) {
#pragma unroll
    for (int o = 32; o > 0; o >>= 1) v += __shfl_xor(v, o);
    return v;
}

// In-place masked softmax over each 2048-wide score row (fp16).
__global__ __launch_bounds__(256) void softmax_kernel(f16* __restrict__ Sm, const int* __restrict__ mask)
{
    const long long row = blockIdx.x;
    const int b = (int)(row >> 11);
    f16* Srow = Sm + row * 2048;
    const int* mrow = mask + b * 2048;
    const int t = threadIdx.x;
    const int w = t >> 6, l = t & 63;

    f16x8 sv = *(const f16x8*)(Srow + t * 8);
    int4 m0 = *(const int4*)(mrow + t * 8);
    int4 m1 = *(const int4*)(mrow + t * 8 + 4);
    int mk[8] = {m0.x, m0.y, m0.z, m0.w, m1.x, m1.y, m1.z, m1.w};
    float v[8];
#pragma unroll
    for (int j = 0; j < 8; j++) v[j] = (float)sv[j];

    float mx = -INFINITY;
#pragma unroll
    for (int j = 0; j < 8; j++) if (mk[j]) mx = fmaxf(mx, v[j]);
    mx = wred_max(mx);
    __shared__ float redm[4], reds[4];
    if (l == 0) redm[w] = mx;
    __syncthreads();
    mx = fmaxf(fmaxf(redm[0], redm[1]), fmaxf(redm[2], redm[3]));

    if (mx == -INFINITY) {
        // reference: all scores == MASK_FILL -> softmax is exactly uniform
        const f16 u = (f16)(1.0f / 2048.0f);
        f16x8 pv;
#pragma unroll
        for (int j = 0; j < 8; j++) pv[j] = u;
        *(f16x8*)(Srow + t * 8) = pv;
        return;
    }

    float e[8];
    float s = 0.f;
#pragma unroll
    for (int j = 0; j < 8; j++) { e[j] = mk[j] ? expf(v[j] - mx) : 0.f; s += e[j]; }
    s = wred_sum(s);
    if (l == 0) reds[w] = s;
    __syncthreads();
    s = reds[0] + reds[1] + reds[2] + reds[3];
    const float inv = 1.0f / s;
    f16x8 pv;
#pragma unroll
    for (int j = 0; j < 8; j++) pv[j] = (f16)(e[j] * inv);
    *(f16x8*)(Srow + t * 8) = pv;
}

extern "C" void kernel_launch(void* const* d_in, const int* in_sizes, int n_in,
                              void* d_out, int out_size, void* d_ws, size_t ws_size,
                              hipStream_t stream)
{
    const float* query = (const float*)d_in[0];
    const float* keyi  = (const float*)d_in[1];
    const float* value = (const float*)d_in[2];
    const float* Wq    = (const float*)d_in[3];
    const float* Wk    = (const float*)d_in[4];
    const float* Wv    = (const float*)d_in[5];
    const int*   mask  = (const int*)d_in[6];
    float* out = (float*)d_out;

    // ws: 5 slots of SH f16 = 167.8 MB (proven footprint).
    //   slot0: Xk -> v -> P-low ; slot1: Xv -> P-high ; slot2: q ;
    //   slot3: Xq -> k ; slot4: wh (6 MB) -> vT
    const long long SH = (long long)8 * 2048 * 1024;
    f16* slot0 = (f16*)d_ws;
    f16* slot1 = slot0 + SH;
    f16* slot2 = slot0 + 2 * SH;
    f16* slot3 = slot0 + 3 * SH;
    f16* slot4 = slot0 + 4 * SH;
    f16* wh    = slot4;            // dead before transpose writes vT here
    f16* Pb    = slot0;            // 8*2048*2048 f16 = 2*SH

    const int n4x = (int)(SH / 4);
    const int n4w = 1024 * 1024 / 4;
    const long long zero = 0;
    const long long M1 = 1024 * 1024;

    // 0) W -> f16
    cast3_kernel<<<dim3(128, 1, 3), 256, 0, stream>>>(Wq, Wk, Wv, wh, wh + M1, wh + 2 * M1, n4w);
    // 1) all three X -> f16 in one dispatch
    cast3_kernel<<<dim3(2048, 1, 3), 256, 0, stream>>>(query, keyi, value, slot3, slot0, slot1, n4x);
    // 2) projections: M=16384 N=1024 K=1024 -> grid 64*4=256, gx=4
    gemm_nt_256<1><<<dim3(256, 1, 1), 512, 0, stream>>>(
        slot3, wh, (void*)slot2, 1024, 1024, 1024, 1024, zero, zero, zero, 4);          // q
    gemm_nt_256<1><<<dim3(256, 1, 1), 512, 0, stream>>>(
        slot0, wh + M1, (void*)slot3, 1024, 1024, 1024, 1024, zero, zero, zero, 4);     // k
    gemm_nt_256<1><<<dim3(256, 1, 1), 512, 0, stream>>>(
        slot1, wh + 2 * M1, (void*)slot0, 1024, 1024, 1024, 1024, zero, zero, zero, 4); // v
    // 3) v -> vT (kills wh)
    transpose_v_kernel<<<dim3(32, 16, 8), 256, 0, stream>>>(slot0, slot4);
    // 4) S = q @ k^T per batch: M=N=2048 K=1024 -> grid 8*8=64 per z, gx=8
    gemm_nt_256<1><<<dim3(64, 1, 8), 512, 0, stream>>>(
        slot2, slot3, (void*)Pb, 1024, 1024, 1024, 2048,
        (long long)2048 * 1024, (long long)2048 * 1024, (long long)2048 * 2048, 8);
    // 5) P = masked softmax(S), in place
    softmax_kernel<<<dim3(16384), 256, 0, stream>>>(Pb, mask);
    // 6) context = P @ vT^T: M=2048 N=1024 K=2048 -> grid 8*4=32 per z, gx=4
    gemm_nt_256<0><<<dim3(32, 1, 8), 512, 0, stream>>>(
        Pb, slot4, (void*)out, 2048, 2048, 2048, 1024,
        (long long)2048 * 2048, (long long)1024 * 2048, (long long)2048 * 1024, 4);
}

// Round 9
// 380.245 us; speedup vs baseline: 1.1411x; 1.1411x over previous
//
#include <hip/hip_runtime.h>
#include <hip/hip_fp16.h>
#include <math.h>

typedef _Float16 f16;
typedef _Float16 f16x4 __attribute__((ext_vector_type(4)));
typedef _Float16 f16x8 __attribute__((ext_vector_type(8)));
typedef float f32x4 __attribute__((ext_vector_type(4)));

#define GLOAD_LDS16(g, l)                                                                  \
    __builtin_amdgcn_global_load_lds((const __attribute__((address_space(1))) void*)(g),   \
                                     (__attribute__((address_space(3))) void*)(l), 16, 0, 0)

// Three-source f32 -> f16 cast with independent destinations, blockIdx.z selects.
__global__ __launch_bounds__(256) void cast3_kernel(const float* __restrict__ s0,
                                                    const float* __restrict__ s1,
                                                    const float* __restrict__ s2,
                                                    f16* d0, f16* d1, f16* d2, int n4each)
{
    const int z = blockIdx.z;
    const float* src = (z == 0) ? s0 : (z == 1) ? s1 : s2;
    f16* d = (z == 0) ? d0 : (z == 1) ? d1 : d2;
    const int stride = gridDim.x * blockDim.x;
    for (int i = blockIdx.x * blockDim.x + threadIdx.x; i < n4each; i += stride) {
        float4 v = *(const float4*)(src + (long long)i * 4);
        *(f16x4*)(d + (long long)i * 4) = (f16x4){(f16)v.x, (f16)v.y, (f16)v.z, (f16)v.w};
    }
}

// ============================================================================
// 256x128 tile NT GEMM, BK=32, 512 threads (8 waves 4Mx2N), 48 KiB LDS dbuf
// -> 2-3 blocks/CU (m97 multi-block overlap regime).  Counted vmcnt(3)
// pipeline (round-7 proven skeleton), T2 both-sides swizzle, T5 setprio.
// C[M,N] = A[M,K](f16) * B[N,K](f16)^T.  M % 256 == 0, N % 128 == 0, K % 32 == 0.
// Grid: dim3(nwg, 1, nz), nwg % 8 == 0; gx = N/128.
// ============================================================================
template <int OUTF16>
__global__ __launch_bounds__(512, 4) void gemm_nt_k(
    const f16* __restrict__ Ab, const f16* __restrict__ Bb, void* __restrict__ Cb,
    int K, int lda, int ldb, int ldc,
    long long sA, long long sB, long long sC, int gx)
{
    // A: [buf][256 rows][32 k] (flat), B: [buf][128 rows][32 k]; rows are 64 B.
    __shared__ __align__(16) f16 As[2][256 * 32];
    __shared__ __align__(16) f16 Bs[2][128 * 32];

    // XCD-aware bijective swizzle (nwg % 8 == 0).
    const int nwg = gridDim.x;
    const int swz = (blockIdx.x & 7) * (nwg >> 3) + (blockIdx.x >> 3);
    const int bx = swz % gx, by = swz / gx;

    const int z = blockIdx.z;
    const char* pA = (const char*)(Ab + z * sA + (long long)by * 256 * lda);
    const char* pB = (const char*)(Bb + z * sB + (long long)bx * 128 * ldb);
    const long long lda2 = (long long)lda * 2, ldb2 = (long long)ldb * 2;

    const int tid = threadIdx.x;
    const int w = tid >> 6, l = tid & 63;
    const int wr = w >> 1, wc = w & 1;          // 4M x 2N wave grid, wave tile 64x64

    // Staging: 4 threads per 64B row.  T2: LDS linear, global col inverse-swizzled.
    const int r0s = tid >> 2;                   // A round 0 / B rows (0..127)
    const int r1s = 128 + r0s;                  // A round 1 rows (128..255)
    const int cb = (tid & 3) * 16;
    const int c0s = cb ^ ((r0s & 3) << 4);
    const int c1s = cb ^ ((r1s & 3) << 4);

#define STAGE(c, kt)                                                                      \
    do {                                                                                  \
        const long long kb_ = (long long)(kt) * 64;                                       \
        GLOAD_LDS16(pA + (long long)r0s * lda2 + kb_ + c0s, &As[c][(long long)tid * 8]);  \
        GLOAD_LDS16(pA + (long long)r1s * lda2 + kb_ + c1s, &As[c][(512 + (long long)tid) * 8]); \
        GLOAD_LDS16(pB + (long long)r0s * ldb2 + kb_ + c0s, &Bs[c][(long long)tid * 8]);  \
    } while (0)

    // Swizzled frag reads; row*64 + (kbyte ^ ((row&3)<<4)), kbyte in [0,64).
#define FRAG_A(c, row, kbyte)                                                             \
    (*(const f16x8*)((const char*)&As[c][0] + ((row) * 64) + ((kbyte) ^ (((row) & 3) << 4))))
#define FRAG_B(c, row, kbyte)                                                             \
    (*(const f16x8*)((const char*)&Bs[c][0] + ((row) * 64) + ((kbyte) ^ (((row) & 3) << 4))))

    f32x4 acc[4][4];
#pragma unroll
    for (int i = 0; i < 4; i++)
#pragma unroll
        for (int j = 0; j < 4; j++) acc[i][j] = (f32x4){0.f, 0.f, 0.f, 0.f};

    const int lr = l & 15;          // frag row within 16
    const int lkb = (l >> 4) * 16;  // frag k sub-offset in bytes (4 groups x 8 f16 = k32)

    const int nt = K >> 5;
    STAGE(0, 0);
    for (int t = 0; t < nt; ++t) {
        const int buf = t & 1;
        if (t + 1 < nt) {
            STAGE(buf ^ 1, t + 1);
            asm volatile("s_waitcnt vmcnt(3)" ::: "memory");   // tile t landed; t+1 in flight
        } else {
            asm volatile("s_waitcnt vmcnt(0)" ::: "memory");   // tail drain
        }
        __builtin_amdgcn_s_barrier();                           // publish tile t
        __builtin_amdgcn_sched_barrier(0);

        f16x8 bf[4], af[4];
#pragma unroll
        for (int fc = 0; fc < 4; fc++) bf[fc] = FRAG_B(buf, wc * 64 + fc * 16 + lr, lkb);
#pragma unroll
        for (int fq = 0; fq < 4; fq++) af[fq] = FRAG_A(buf, wr * 64 + fq * 16 + lr, lkb);

        __builtin_amdgcn_s_setprio(1);
#pragma unroll
        for (int fq = 0; fq < 4; fq++)
#pragma unroll
            for (int fc = 0; fc < 4; fc++)
                acc[fq][fc] = __builtin_amdgcn_mfma_f32_16x16x32_f16(af[fq], bf[fc], acc[fq][fc], 0, 0, 0);
        __builtin_amdgcn_s_setprio(0);

        __builtin_amdgcn_s_barrier();                           // all reads done before overwrite
        __builtin_amdgcn_sched_barrier(0);
    }
#undef STAGE
#undef FRAG_A
#undef FRAG_B

    // C/D 16x16 layout: col = lane&15, row = (lane>>4)*4 + i  (HW-verified)
    const int row_l = (l >> 4) * 4;
    const long long gr0 = (long long)by * 256 + wr * 64;
    const int gc0 = bx * 128 + wc * 64;
    if (OUTF16) {
        f16* C = (f16*)Cb + z * sC;
#pragma unroll
        for (int fq = 0; fq < 4; fq++)
#pragma unroll
            for (int fc = 0; fc < 4; fc++)
#pragma unroll
                for (int i = 0; i < 4; i++)
                    C[(gr0 + fq * 16 + row_l + i) * ldc + gc0 + fc * 16 + lr] = (f16)acc[fq][fc][i];
    } else {
        float* C = (float*)Cb + z * sC;
#pragma unroll
        for (int fq = 0; fq < 4; fq++)
#pragma unroll
            for (int fc = 0; fc < 4; fc++)
#pragma unroll
                for (int i = 0; i < 4; i++)
                    C[(gr0 + fq * 16 + row_l + i) * ldc + gc0 + fc * 16 + lr] = acc[fq][fc][i];
    }
}

// vT[b][o][s] = v[b][s][o], 64x64 LDS tiles.
__global__ __launch_bounds__(256) void transpose_v_kernel(const f16* __restrict__ v, f16* __restrict__ vT)
{
    __shared__ f16 tile[64][72];
    const int b = blockIdx.z;
    const int s0 = blockIdx.x * 64, o0 = blockIdx.y * 64;
    const int t = threadIdx.x;
    const int r = t >> 2, c = (t & 3) * 16;
    const f16* src = v + ((long long)b * 2048 + s0) * 1024 + o0;
    *(f16x8*)&tile[r][c]     = *(const f16x8*)(src + (long long)r * 1024 + c);
    *(f16x8*)&tile[r][c + 8] = *(const f16x8*)(src + (long long)r * 1024 + c + 8);
    __syncthreads();
    f16* dst = vT + ((long long)b * 1024 + o0) * 2048 + s0;
    f16 buf[16];
#pragma unroll
    for (int j = 0; j < 16; j++) buf[j] = tile[c + j][r];
    *(f16x8*)(dst + (long long)r * 2048 + c)     = *(f16x8*)&buf[0];
    *(f16x8*)(dst + (long long)r * 2048 + c + 8) = *(f16x8*)&buf[8];
}

__device__ __forceinline__ float wred_max(float v) {
#pragma unroll
    for (int o = 32; o > 0; o >>= 1) v = fmaxf(v, __shfl_xor(v, o));
    return v;
}
__device__ __forceinline__ float wred_sum(float v) {
#pragma unroll
    for (int o = 32; o > 0; o >>= 1) v += __shfl_xor(v, o);
    return v;
}

// In-place masked softmax over each 2048-wide score row (fp16).
__global__ __launch_bounds__(256) void softmax_kernel(f16* __restrict__ Sm, const int* __restrict__ mask)
{
    const long long row = blockIdx.x;
    const int b = (int)(row >> 11);
    f16* Srow = Sm + row * 2048;
    const int* mrow = mask + b * 2048;
    const int t = threadIdx.x;
    const int w = t >> 6, l = t & 63;

    f16x8 sv = *(const f16x8*)(Srow + t * 8);
    int4 m0 = *(const int4*)(mrow + t * 8);
    int4 m1 = *(const int4*)(mrow + t * 8 + 4);
    int mk[8] = {m0.x, m0.y, m0.z, m0.w, m1.x, m1.y, m1.z, m1.w};
    float v[8];
#pragma unroll
    for (int j = 0; j < 8; j++) v[j] = (float)sv[j];

    float mx = -INFINITY;
#pragma unroll
    for (int j = 0; j < 8; j++) if (mk[j]) mx = fmaxf(mx, v[j]);
    mx = wred_max(mx);
    __shared__ float redm[4], reds[4];
    if (l == 0) redm[w] = mx;
    __syncthreads();
    mx = fmaxf(fmaxf(redm[0], redm[1]), fmaxf(redm[2], redm[3]));

    if (mx == -INFINITY) {
        // reference: all scores == MASK_FILL -> softmax is exactly uniform
        const f16 u = (f16)(1.0f / 2048.0f);
        f16x8 pv;
#pragma unroll
        for (int j = 0; j < 8; j++) pv[j] = u;
        *(f16x8*)(Srow + t * 8) = pv;
        return;
    }

    float e[8];
    float s = 0.f;
#pragma unroll
    for (int j = 0; j < 8; j++) { e[j] = mk[j] ? expf(v[j] - mx) : 0.f; s += e[j]; }
    s = wred_sum(s);
    if (l == 0) reds[w] = s;
    __syncthreads();
    s = reds[0] + reds[1] + reds[2] + reds[3];
    const float inv = 1.0f / s;
    f16x8 pv;
#pragma unroll
    for (int j = 0; j < 8; j++) pv[j] = (f16)(e[j] * inv);
    *(f16x8*)(Srow + t * 8) = pv;
}

extern "C" void kernel_launch(void* const* d_in, const int* in_sizes, int n_in,
                              void* d_out, int out_size, void* d_ws, size_t ws_size,
                              hipStream_t stream)
{
    const float* query = (const float*)d_in[0];
    const float* keyi  = (const float*)d_in[1];
    const float* value = (const float*)d_in[2];
    const float* Wq    = (const float*)d_in[3];
    const float* Wk    = (const float*)d_in[4];
    const float* Wv    = (const float*)d_in[5];
    const int*   mask  = (const int*)d_in[6];
    float* out = (float*)d_out;

    // ws: 5 slots of SH f16 = 167.8 MB (proven footprint).
    //   slot0: Xk -> v -> P-low ; slot1: Xv -> P-high ; slot2: q ;
    //   slot3: Xq -> k ; slot4: wh (6 MB) -> vT
    const long long SH = (long long)8 * 2048 * 1024;
    f16* slot0 = (f16*)d_ws;
    f16* slot1 = slot0 + SH;
    f16* slot2 = slot0 + 2 * SH;
    f16* slot3 = slot0 + 3 * SH;
    f16* slot4 = slot0 + 4 * SH;
    f16* wh    = slot4;            // dead before transpose writes vT here
    f16* Pb    = slot0;            // 8*2048*2048 f16 = 2*SH

    const int n4x = (int)(SH / 4);
    const int n4w = 1024 * 1024 / 4;
    const long long zero = 0;
    const long long M1 = 1024 * 1024;

    // 0) W -> f16
    cast3_kernel<<<dim3(128, 1, 3), 256, 0, stream>>>(Wq, Wk, Wv, wh, wh + M1, wh + 2 * M1, n4w);
    // 1) all three X -> f16 in one dispatch
    cast3_kernel<<<dim3(2048, 1, 3), 256, 0, stream>>>(query, keyi, value, slot3, slot0, slot1, n4x);
    // 2) projections: M=16384 N=1024 K=1024 -> grid 64*8=512, gx=8
    gemm_nt_k<1><<<dim3(512, 1, 1), 512, 0, stream>>>(
        slot3, wh, (void*)slot2, 1024, 1024, 1024, 1024, zero, zero, zero, 8);          // q
    gemm_nt_k<1><<<dim3(512, 1, 1), 512, 0, stream>>>(
        slot0, wh + M1, (void*)slot3, 1024, 1024, 1024, 1024, zero, zero, zero, 8);     // k
    gemm_nt_k<1><<<dim3(512, 1, 1), 512, 0, stream>>>(
        slot1, wh + 2 * M1, (void*)slot0, 1024, 1024, 1024, 1024, zero, zero, zero, 8); // v
    // 3) v -> vT (kills wh)
    transpose_v_kernel<<<dim3(32, 16, 8), 256, 0, stream>>>(slot0, slot4);
    // 4) S = q @ k^T per batch: M=N=2048 K=1024 -> grid 8*16=128 per z, gx=16
    gemm_nt_k<1><<<dim3(128, 1, 8), 512, 0, stream>>>(
        slot2, slot3, (void*)Pb, 1024, 1024, 1024, 2048,
        (long long)2048 * 1024, (long long)2048 * 1024, (long long)2048 * 2048, 16);
    // 5) P = masked softmax(S), in place
    softmax_kernel<<<dim3(16384), 256, 0, stream>>>(Pb, mask);
    // 6) context = P @ vT^T: M=2048 N=1024 K=2048 -> grid 8*8=64 per z, gx=8
    gemm_nt_k<0><<<dim3(64, 1, 8), 512, 0, stream>>>(
        Pb, slot4, (void*)out, 2048, 2048, 2048, 1024,
        (long long)2048 * 2048, (long long)1024 * 2048, (long long)2048 * 1024, 8);
}

// Round 10
// 332.595 us; speedup vs baseline: 1.3046x; 1.1433x over previous
//
#include <hip/hip_runtime.h>
#include <hip/hip_fp16.h>
#include <math.h>

typedef _Float16 f16;
typedef _Float16 f16x4 __attribute__((ext_vector_type(4)));
typedef _Float16 f16x8 __attribute__((ext_vector_type(8)));
typedef float f32x4 __attribute__((ext_vector_type(4)));

#define GLOAD_LDS16(g, l)                                                                  \
    __builtin_amdgcn_global_load_lds((const __attribute__((address_space(1))) void*)(g),   \
                                     (__attribute__((address_space(3))) void*)(l), 16, 0, 0)

// Three-source f32 -> f16 cast with independent destinations, blockIdx.z selects.
__global__ __launch_bounds__(256) void cast3_kernel(const float* __restrict__ s0,
                                                    const float* __restrict__ s1,
                                                    const float* __restrict__ s2,
                                                    f16* d0, f16* d1, f16* d2, int n4each)
{
    const int z = blockIdx.z;
    const float* src = (z == 0) ? s0 : (z == 1) ? s1 : s2;
    f16* d = (z == 0) ? d0 : (z == 1) ? d1 : d2;
    const int stride = gridDim.x * blockDim.x;
    for (int i = blockIdx.x * blockDim.x + threadIdx.x; i < n4each; i += stride) {
        float4 v = *(const float4*)(src + (long long)i * 4);
        *(f16x4*)(d + (long long)i * 4) = (f16x4){(f16)v.x, (f16)v.y, (f16)v.z, (f16)v.w};
    }
}

// ============================================================================
// 256x128 tile NT GEMM, BK=64, 512 threads (8 waves 4Mx2N), SINGLE-buffered
// 48 KiB LDS -> 3 blocks/CU (m97 regime: {STAGE; sync; compute; sync}, no
// explicit waitcnt — cross-block overlap absorbs the stage stall; compiler
// interleaves the 16 ds_read / 32 MFMA body via fine lgkmcnt).  T2 both-sides
// swizzle with full 8-row XOR (rows are 128 B).  XCD swizzle.  No setprio
// (m190: hurts pre-8-phase GEMM).
// C[M,N] = A[M,K](f16) * B[N,K](f16)^T.  M % 256 == 0, N % 128 == 0, K % 64 == 0.
// Grid: dim3(nwg, 1, nz), nwg % 8 == 0; gx = N/128.
// ============================================================================
template <int OUTF16>
__global__ __launch_bounds__(512, 2) void gemm_nt_k(
    const f16* __restrict__ Ab, const f16* __restrict__ Bb, void* __restrict__ Cb,
    int K, int lda, int ldb, int ldc,
    long long sA, long long sB, long long sC, int gx)
{
    // A: [256 rows][64 k] f16 (rows 128 B), B: [128 rows][64 k].  Linear for
    // global_load_lds; swizzle lives in the global source column + frag reads.
    __shared__ __align__(16) f16 As[256 * 64];
    __shared__ __align__(16) f16 Bs[128 * 64];

    // XCD-aware bijective swizzle (nwg % 8 == 0).
    const int nwg = gridDim.x;
    const int swz = (blockIdx.x & 7) * (nwg >> 3) + (blockIdx.x >> 3);
    const int bx = swz % gx, by = swz / gx;

    const int z = blockIdx.z;
    const char* pA = (const char*)(Ab + z * sA + (long long)by * 256 * lda);
    const char* pB = (const char*)(Bb + z * sB + (long long)bx * 128 * ldb);
    const long long lda2 = (long long)lda * 2, ldb2 = (long long)ldb * 2;

    const int tid = threadIdx.x;
    const int w = tid >> 6, l = tid & 63;
    const int wr = w >> 1, wc = w & 1;          // 4M x 2N wave grid, wave tile 64x64

    f32x4 acc[4][4];
#pragma unroll
    for (int i = 0; i < 4; i++)
#pragma unroll
        for (int j = 0; j < 4; j++) acc[i][j] = (f32x4){0.f, 0.f, 0.f, 0.f};

    const int lr = l & 15;          // frag row within 16
    const int lkb = (l >> 4) * 16;  // frag k sub-offset in bytes

    // Swizzled frag reads: addr = row*128 + (kbyte ^ ((row&7)<<4)), kbyte in [0,128).
#define FRAG_A(row, kbyte)                                                                \
    (*(const f16x8*)((const char*)&As[0] + ((row) * 128) + ((kbyte) ^ (((row) & 7) << 4))))
#define FRAG_B(row, kbyte)                                                                \
    (*(const f16x8*)((const char*)&Bs[0] + ((row) * 128) + ((kbyte) ^ (((row) & 7) << 4))))

    const int nt = K >> 6;
    for (int t = 0; t < nt; ++t) {
        const long long kb = (long long)t * 128;   // byte offset of this K-tile
        // STAGE: A = 4 chunks, B = 2 chunks; chunk c -> row = c>>3, col16 = c&7.
        // T2: LDS linear dest; global source column inverse-swizzled.
#pragma unroll
        for (int i = 0; i < 4; i++) {
            const int c = i * 512 + tid;
            const int row = c >> 3;
            const int col = ((c & 7) * 16) ^ ((row & 7) << 4);
            GLOAD_LDS16(pA + (long long)row * lda2 + kb + col, &As[(long long)c * 8]);
        }
#pragma unroll
        for (int i = 0; i < 2; i++) {
            const int c = i * 512 + tid;
            const int row = c >> 3;
            const int col = ((c & 7) * 16) ^ ((row & 7) << 4);
            GLOAD_LDS16(pB + (long long)row * ldb2 + kb + col, &Bs[(long long)c * 8]);
        }
        __syncthreads();   // drains vmcnt (gload_lds) + publishes tile

        f16x8 bf[4][2], af[4][2];
#pragma unroll
        for (int fc = 0; fc < 4; fc++)
#pragma unroll
            for (int ks = 0; ks < 2; ks++)
                bf[fc][ks] = FRAG_B(wc * 64 + fc * 16 + lr, ks * 64 + lkb);
#pragma unroll
        for (int fq = 0; fq < 4; fq++)
#pragma unroll
            for (int ks = 0; ks < 2; ks++)
                af[fq][ks] = FRAG_A(wr * 64 + fq * 16 + lr, ks * 64 + lkb);

#pragma unroll
        for (int fq = 0; fq < 4; fq++)
#pragma unroll
            for (int fc = 0; fc < 4; fc++)
#pragma unroll
                for (int ks = 0; ks < 2; ks++)
                    acc[fq][fc] = __builtin_amdgcn_mfma_f32_16x16x32_f16(
                        af[fq][ks], bf[fc][ks], acc[fq][fc], 0, 0, 0);

        __syncthreads();   // all reads done before next STAGE overwrites
    }
#undef FRAG_A
#undef FRAG_B

    // C/D 16x16 layout: col = lane&15, row = (lane>>4)*4 + i  (HW-verified)
    const int row_l = (l >> 4) * 4;
    const long long gr0 = (long long)by * 256 + wr * 64;
    const int gc0 = bx * 128 + wc * 64;
    if (OUTF16) {
        f16* C = (f16*)Cb + z * sC;
#pragma unroll
        for (int fq = 0; fq < 4; fq++)
#pragma unroll
            for (int fc = 0; fc < 4; fc++)
#pragma unroll
                for (int i = 0; i < 4; i++)
                    C[(gr0 + fq * 16 + row_l + i) * ldc + gc0 + fc * 16 + lr] = (f16)acc[fq][fc][i];
    } else {
        float* C = (float*)Cb + z * sC;
#pragma unroll
        for (int fq = 0; fq < 4; fq++)
#pragma unroll
            for (int fc = 0; fc < 4; fc++)
#pragma unroll
                for (int i = 0; i < 4; i++)
                    C[(gr0 + fq * 16 + row_l + i) * ldc + gc0 + fc * 16 + lr] = acc[fq][fc][i];
    }
}

// vT[b][o][s] = v[b][s][o], 64x64 LDS tiles.
__global__ __launch_bounds__(256) void transpose_v_kernel(const f16* __restrict__ v, f16* __restrict__ vT)
{
    __shared__ f16 tile[64][72];
    const int b = blockIdx.z;
    const int s0 = blockIdx.x * 64, o0 = blockIdx.y * 64;
    const int t = threadIdx.x;
    const int r = t >> 2, c = (t & 3) * 16;
    const f16* src = v + ((long long)b * 2048 + s0) * 1024 + o0;
    *(f16x8*)&tile[r][c]     = *(const f16x8*)(src + (long long)r * 1024 + c);
    *(f16x8*)&tile[r][c + 8] = *(const f16x8*)(src + (long long)r * 1024 + c + 8);
    __syncthreads();
    f16* dst = vT + ((long long)b * 1024 + o0) * 2048 + s0;
    f16 buf[16];
#pragma unroll
    for (int j = 0; j < 16; j++) buf[j] = tile[c + j][r];
    *(f16x8*)(dst + (long long)r * 2048 + c)     = *(f16x8*)&buf[0];
    *(f16x8*)(dst + (long long)r * 2048 + c + 8) = *(f16x8*)&buf[8];
}

__device__ __forceinline__ float wred_max(float v) {
#pragma unroll
    for (int o = 32; o > 0; o >>= 1) v = fmaxf(v, __shfl_xor(v, o));
    return v;
}
__device__ __forceinline__ float wred_sum(float v) {
#pragma unroll
    for (int o = 32; o > 0; o >>= 1) v += __shfl_xor(v, o);
    return v;
}

// In-place masked softmax over each 2048-wide score row (fp16).
__global__ __launch_bounds__(256) void softmax_kernel(f16* __restrict__ Sm, const int* __restrict__ mask)
{
    const long long row = blockIdx.x;
    const int b = (int)(row >> 11);
    f16* Srow = Sm + row * 2048;
    const int* mrow = mask + b * 2048;
    const int t = threadIdx.x;
    const int w = t >> 6, l = t & 63;

    f16x8 sv = *(const f16x8*)(Srow + t * 8);
    int4 m0 = *(const int4*)(mrow + t * 8);
    int4 m1 = *(const int4*)(mrow + t * 8 + 4);
    int mk[8] = {m0.x, m0.y, m0.z, m0.w, m1.x, m1.y, m1.z, m1.w};
    float v[8];
#pragma unroll
    for (int j = 0; j < 8; j++) v[j] = (float)sv[j];

    float mx = -INFINITY;
#pragma unroll
    for (int j = 0; j < 8; j++) if (mk[j]) mx = fmaxf(mx, v[j]);
    mx = wred_max(mx);
    __shared__ float redm[4], reds[4];
    if (l == 0) redm[w] = mx;
    __syncthreads();
    mx = fmaxf(fmaxf(redm[0], redm[1]), fmaxf(redm[2], redm[3]));

    if (mx == -INFINITY) {
        // reference: all scores == MASK_FILL -> softmax is exactly uniform
        const f16 u = (f16)(1.0f / 2048.0f);
        f16x8 pv;
#pragma unroll
        for (int j = 0; j < 8; j++) pv[j] = u;
        *(f16x8*)(Srow + t * 8) = pv;
        return;
    }

    float e[8];
    float s = 0.f;
#pragma unroll
    for (int j = 0; j < 8; j++) { e[j] = mk[j] ? expf(v[j] - mx) : 0.f; s += e[j]; }
    s = wred_sum(s);
    if (l == 0) reds[w] = s;
    __syncthreads();
    s = reds[0] + reds[1] + reds[2] + reds[3];
    const float inv = 1.0f / s;
    f16x8 pv;
#pragma unroll
    for (int j = 0; j < 8; j++) pv[j] = (f16)(e[j] * inv);
    *(f16x8*)(Srow + t * 8) = pv;
}

extern "C" void kernel_launch(void* const* d_in, const int* in_sizes, int n_in,
                              void* d_out, int out_size, void* d_ws, size_t ws_size,
                              hipStream_t stream)
{
    const float* query = (const float*)d_in[0];
    const float* keyi  = (const float*)d_in[1];
    const float* value = (const float*)d_in[2];
    const float* Wq    = (const float*)d_in[3];
    const float* Wk    = (const float*)d_in[4];
    const float* Wv    = (const float*)d_in[5];
    const int*   mask  = (const int*)d_in[6];
    float* out = (float*)d_out;

    // ws: 5 slots of SH f16 = 167.8 MB (proven footprint).
    //   slot0: Xk -> v -> P-low ; slot1: Xv -> P-high ; slot2: q ;
    //   slot3: Xq -> k ; slot4: wh (6 MB) -> vT
    const long long SH = (long long)8 * 2048 * 1024;
    f16* slot0 = (f16*)d_ws;
    f16* slot1 = slot0 + SH;
    f16* slot2 = slot0 + 2 * SH;
    f16* slot3 = slot0 + 3 * SH;
    f16* slot4 = slot0 + 4 * SH;
    f16* wh    = slot4;            // dead before transpose writes vT here
    f16* Pb    = slot0;            // 8*2048*2048 f16 = 2*SH

    const int n4x = (int)(SH / 4);
    const int n4w = 1024 * 1024 / 4;
    const long long zero = 0;
    const long long M1 = 1024 * 1024;

    // 0) W -> f16
    cast3_kernel<<<dim3(128, 1, 3), 256, 0, stream>>>(Wq, Wk, Wv, wh, wh + M1, wh + 2 * M1, n4w);
    // 1) all three X -> f16 in one dispatch
    cast3_kernel<<<dim3(2048, 1, 3), 256, 0, stream>>>(query, keyi, value, slot3, slot0, slot1, n4x);
    // 2) projections: M=16384 N=1024 K=1024 -> grid 64*8=512, gx=8
    gemm_nt_k<1><<<dim3(512, 1, 1), 512, 0, stream>>>(
        slot3, wh, (void*)slot2, 1024, 1024, 1024, 1024, zero, zero, zero, 8);          // q
    gemm_nt_k<1><<<dim3(512, 1, 1), 512, 0, stream>>>(
        slot0, wh + M1, (void*)slot3, 1024, 1024, 1024, 1024, zero, zero, zero, 8);     // k
    gemm_nt_k<1><<<dim3(512, 1, 1), 512, 0, stream>>>(
        slot1, wh + 2 * M1, (void*)slot0, 1024, 1024, 1024, 1024, zero, zero, zero, 8); // v
    // 3) v -> vT (kills wh)
    transpose_v_kernel<<<dim3(32, 16, 8), 256, 0, stream>>>(slot0, slot4);
    // 4) S = q @ k^T per batch: M=N=2048 K=1024 -> grid 8*16=128 per z, gx=16
    gemm_nt_k<1><<<dim3(128, 1, 8), 512, 0, stream>>>(
        slot2, slot3, (void*)Pb, 1024, 1024, 1024, 2048,
        (long long)2048 * 1024, (long long)2048 * 1024, (long long)2048 * 2048, 16);
    // 5) P = masked softmax(S), in place
    softmax_kernel<<<dim3(16384), 256, 0, stream>>>(Pb, mask);
    // 6) context = P @ vT^T: M=2048 N=1024 K=2048 -> grid 8*8=64 per z, gx=8
    gemm_nt_k<0><<<dim3(64, 1, 8), 512, 0, stream>>>(
        Pb, slot4, (void*)out, 2048, 2048, 2048, 1024,
        (long long)2048 * 2048, (long long)1024 * 2048, (long long)2048 * 1024, 8);
}

// Round 11
// 325.160 us; speedup vs baseline: 1.3345x; 1.0229x over previous
//
#include <hip/hip_runtime.h>
#include <hip/hip_fp16.h>
#include <math.h>

typedef _Float16 f16;
typedef _Float16 f16x4 __attribute__((ext_vector_type(4)));
typedef _Float16 f16x8 __attribute__((ext_vector_type(8)));
typedef float f32x4 __attribute__((ext_vector_type(4)));

#define GLOAD_LDS16(g, l)                                                                  \
    __builtin_amdgcn_global_load_lds((const __attribute__((address_space(1))) void*)(g),   \
                                     (__attribute__((address_space(3))) void*)(l), 16, 0, 0)

// Three-source f32 -> f16 cast, 16 elems/thread/iter (4 independent float4 loads
// -> 2 f16x8 stores) for memory-level parallelism; latency-bound fix (r10 PMC:
// VALUBusy 3.9%, HBM 33% -> 1 load in flight per wave was the limiter).
__global__ __launch_bounds__(256) void cast3_kernel(const float* __restrict__ s0,
                                                    const float* __restrict__ s1,
                                                    const float* __restrict__ s2,
                                                    f16* d0, f16* d1, f16* d2, int n16each)
{
    const int z = blockIdx.z;
    const float* src = (z == 0) ? s0 : (z == 1) ? s1 : s2;
    f16* dst = (z == 0) ? d0 : (z == 1) ? d1 : d2;
    const int stride = gridDim.x * blockDim.x;
    for (int i = blockIdx.x * blockDim.x + threadIdx.x; i < n16each; i += stride) {
        const float4* sp = (const float4*)(src + (long long)i * 16);
        float4 a = sp[0], b = sp[1], c = sp[2], d4 = sp[3];   // 4 independent loads
        f16x8 lo = {(f16)a.x, (f16)a.y, (f16)a.z, (f16)a.w,
                    (f16)b.x, (f16)b.y, (f16)b.z, (f16)b.w};
        f16x8 hi = {(f16)c.x, (f16)c.y, (f16)c.z, (f16)c.w,
                    (f16)d4.x, (f16)d4.y, (f16)d4.z, (f16)d4.w};
        f16x8* dp = (f16x8*)(dst + (long long)i * 16);
        dp[0] = lo;
        dp[1] = hi;
    }
}

// ============================================================================
// 256x128 tile NT GEMM, BK=64, 512 threads (8 waves 4Mx2N), SINGLE-buffered
// 48 KiB LDS (m97 regime, r10-proven: 953 TF, 0 bank conflicts).
// TRANSC=1: epilogue writes C TRANSPOSED per-batch (vT[b][o][s]) via LDS
// retiling — fuses the v-transpose into the v-projection.
// C[M,N] = A[M,K](f16) * B[N,K](f16)^T.  M % 256 == 0, N % 128 == 0, K % 64 == 0.
// Grid: dim3(nwg, 1, nz), nwg % 8 == 0; gx = N/128.
// ============================================================================
template <int OUTF16, int TRANSC>
__global__ __launch_bounds__(512, 2) void gemm_nt_k(
    const f16* __restrict__ Ab, const f16* __restrict__ Bb, void* __restrict__ Cb,
    int K, int lda, int ldb, int ldc,
    long long sA, long long sB, long long sC, int gx)
{
    // Unified LDS: A = smem[0..16384) (256 rows x 64 k), B = smem[16384..24576)
    // (128 rows x 64 k); rows are 128 B.  Epilogue (TRANSC) reuses smem as
    // [128 o][136 s] f16 (padded stride vs bank conflicts).
    __shared__ __align__(16) f16 smem[256 * 64 + 128 * 64];

    // XCD-aware bijective swizzle (nwg % 8 == 0).
    const int nwg = gridDim.x;
    const int swz = (blockIdx.x & 7) * (nwg >> 3) + (blockIdx.x >> 3);
    const int bx = swz % gx, by = swz / gx;

    const int z = blockIdx.z;
    const char* pA = (const char*)(Ab + z * sA + (long long)by * 256 * lda);
    const char* pB = (const char*)(Bb + z * sB + (long long)bx * 128 * ldb);
    const long long lda2 = (long long)lda * 2, ldb2 = (long long)ldb * 2;

    const int tid = threadIdx.x;
    const int w = tid >> 6, l = tid & 63;
    const int wr = w >> 1, wc = w & 1;          // 4M x 2N wave grid, wave tile 64x64

    f32x4 acc[4][4];
#pragma unroll
    for (int i = 0; i < 4; i++)
#pragma unroll
        for (int j = 0; j < 4; j++) acc[i][j] = (f32x4){0.f, 0.f, 0.f, 0.f};

    const int lr = l & 15;          // frag row within 16
    const int lkb = (l >> 4) * 16;  // frag k sub-offset in bytes

    // Swizzled frag reads: addr = row*128 + (kbyte ^ ((row&7)<<4)), kbyte in [0,128).
#define FRAG_A(row, kbyte)                                                                \
    (*(const f16x8*)((const char*)&smem[0] + ((row) * 128) + ((kbyte) ^ (((row) & 7) << 4))))
#define FRAG_B(row, kbyte)                                                                \
    (*(const f16x8*)((const char*)&smem[0] + 32768 + ((row) * 128) + ((kbyte) ^ (((row) & 7) << 4))))

    const int nt = K >> 6;
    for (int t = 0; t < nt; ++t) {
        const long long kb = (long long)t * 128;   // byte offset of this K-tile
        // STAGE: A = 4 chunks, B = 2 chunks; chunk c -> row = c>>3, col16 = c&7.
        // T2: LDS linear dest; global source column inverse-swizzled.
#pragma unroll
        for (int i = 0; i < 4; i++) {
            const int c = i * 512 + tid;
            const int row = c >> 3;
            const int col = ((c & 7) * 16) ^ ((row & 7) << 4);
            GLOAD_LDS16(pA + (long long)row * lda2 + kb + col, &smem[(long long)c * 8]);
        }
#pragma unroll
        for (int i = 0; i < 2; i++) {
            const int c = i * 512 + tid;
            const int row = c >> 3;
            const int col = ((c & 7) * 16) ^ ((row & 7) << 4);
            GLOAD_LDS16(pB + (long long)row * ldb2 + kb + col, &smem[16384 + (long long)c * 8]);
        }
        __syncthreads();   // drains vmcnt (gload_lds) + publishes tile

        f16x8 bf[4][2], af[4][2];
#pragma unroll
        for (int fc = 0; fc < 4; fc++)
#pragma unroll
            for (int ks = 0; ks < 2; ks++)
                bf[fc][ks] = FRAG_B(wc * 64 + fc * 16 + lr, ks * 64 + lkb);
#pragma unroll
        for (int fq = 0; fq < 4; fq++)
#pragma unroll
            for (int ks = 0; ks < 2; ks++)
                af[fq][ks] = FRAG_A(wr * 64 + fq * 16 + lr, ks * 64 + lkb);

#pragma unroll
        for (int fq = 0; fq < 4; fq++)
#pragma unroll
            for (int fc = 0; fc < 4; fc++)
#pragma unroll
                for (int ks = 0; ks < 2; ks++)
                    acc[fq][fc] = __builtin_amdgcn_mfma_f32_16x16x32_f16(
                        af[fq][ks], bf[fc][ks], acc[fq][fc], 0, 0, 0);

        __syncthreads();   // all reads done before next STAGE overwrites
    }
#undef FRAG_A
#undef FRAG_B

    // C/D 16x16 layout: col = lane&15, row = (lane>>4)*4 + i  (HW-verified)
    const int row_l = (l >> 4) * 4;
    const long long gr0 = (long long)by * 256 + wr * 64;   // flat output row base of this wave
    const int gc0 = bx * 128 + wc * 64;

    if (TRANSC) {
        // Write vT[b][o][s] (s within batch).  Block covers flat rows
        // [by*256, +256) (one batch: 256 | 2048) and cols [bx*128, +128).
        // Two passes over s-halves of 128; LDS retile [128 o][136 s].
        const long long blk_r0 = (long long)by * 256;
        const int b = (int)(blk_r0 >> 11);
        const int s_base = (int)(blk_r0 & 2047);
        f16* vTp = (f16*)Cb + (long long)b * 1024 * 2048;
#pragma unroll
        for (int h = 0; h < 2; h++) {
            __syncthreads();
            if ((wr >> 1) == h) {
                const int s64 = (wr & 1) * 64;
#pragma unroll
                for (int fq = 0; fq < 4; fq++)
#pragma unroll
                    for (int fc = 0; fc < 4; fc++)
#pragma unroll
                        for (int i = 0; i < 4; i++)
                            smem[(wc * 64 + fc * 16 + lr) * 136 + s64 + fq * 16 + row_l + i] =
                                (f16)acc[fq][fc][i];
            }
            __syncthreads();
#pragma unroll
            for (int j = 0; j < 4; j++) {
                const int c = j * 512 + tid;
                const int o = c >> 4, s8 = (c & 15) * 8;
                f16x8 vv = *(const f16x8*)&smem[o * 136 + s8];
                *(f16x8*)&vTp[((long long)(bx * 128 + o)) * 2048 + s_base + h * 128 + s8] = vv;
            }
        }
    } else if (OUTF16) {
        f16* C = (f16*)Cb + z * sC;
#pragma unroll
        for (int fq = 0; fq < 4; fq++)
#pragma unroll
            for (int fc = 0; fc < 4; fc++)
#pragma unroll
                for (int i = 0; i < 4; i++)
                    C[(gr0 + fq * 16 + row_l + i) * ldc + gc0 + fc * 16 + lr] = (f16)acc[fq][fc][i];
    } else {
        float* C = (float*)Cb + z * sC;
#pragma unroll
        for (int fq = 0; fq < 4; fq++)
#pragma unroll
            for (int fc = 0; fc < 4; fc++)
#pragma unroll
                for (int i = 0; i < 4; i++)
                    C[(gr0 + fq * 16 + row_l + i) * ldc + gc0 + fc * 16 + lr] = acc[fq][fc][i];
    }
}

__device__ __forceinline__ float wred_max(float v) {
#pragma unroll
    for (int o = 32; o > 0; o >>= 1) v = fmaxf(v, __shfl_xor(v, o));
    return v;
}
__device__ __forceinline__ float wred_sum(float v) {
#pragma unroll
    for (int o = 32; o > 0; o >>= 1) v += __shfl_xor(v, o);
    return v;
}

// In-place masked softmax over each 2048-wide score row (fp16).
__global__ __launch_bounds__(256) void softmax_kernel(f16* __restrict__ Sm, const int* __restrict__ mask)
{
    const long long row = blockIdx.x;
    const int b = (int)(row >> 11);
    f16* Srow = Sm + row * 2048;
    const int* mrow = mask + b * 2048;
    const int t = threadIdx.x;
    const int w = t >> 6, l = t & 63;

    f16x8 sv = *(const f16x8*)(Srow + t * 8);
    int4 m0 = *(const int4*)(mrow + t * 8);
    int4 m1 = *(const int4*)(mrow + t * 8 + 4);
    int mk[8] = {m0.x, m0.y, m0.z, m0.w, m1.x, m1.y, m1.z, m1.w};
    float v[8];
#pragma unroll
    for (int j = 0; j < 8; j++) v[j] = (float)sv[j];

    float mx = -INFINITY;
#pragma unroll
    for (int j = 0; j < 8; j++) if (mk[j]) mx = fmaxf(mx, v[j]);
    mx = wred_max(mx);
    __shared__ float redm[4], reds[4];
    if (l == 0) redm[w] = mx;
    __syncthreads();
    mx = fmaxf(fmaxf(redm[0], redm[1]), fmaxf(redm[2], redm[3]));

    if (mx == -INFINITY) {
        // reference: all scores == MASK_FILL -> softmax is exactly uniform
        const f16 u = (f16)(1.0f / 2048.0f);
        f16x8 pv;
#pragma unroll
        for (int j = 0; j < 8; j++) pv[j] = u;
        *(f16x8*)(Srow + t * 8) = pv;
        return;
    }

    float e[8];
    float s = 0.f;
#pragma unroll
    for (int j = 0; j < 8; j++) { e[j] = mk[j] ? expf(v[j] - mx) : 0.f; s += e[j]; }
    s = wred_sum(s);
    if (l == 0) reds[w] = s;
    __syncthreads();
    s = reds[0] + reds[1] + reds[2] + reds[3];
    const float inv = 1.0f / s;
    f16x8 pv;
#pragma unroll
    for (int j = 0; j < 8; j++) pv[j] = (f16)(e[j] * inv);
    *(f16x8*)(Srow + t * 8) = pv;
}

extern "C" void kernel_launch(void* const* d_in, const int* in_sizes, int n_in,
                              void* d_out, int out_size, void* d_ws, size_t ws_size,
                              hipStream_t stream)
{
    const float* query = (const float*)d_in[0];
    const float* keyi  = (const float*)d_in[1];
    const float* value = (const float*)d_in[2];
    const float* Wq    = (const float*)d_in[3];
    const float* Wk    = (const float*)d_in[4];
    const float* Wv    = (const float*)d_in[5];
    const int*   mask  = (const int*)d_in[6];
    float* out = (float*)d_out;

    // ws: 5 slots of SH f16 = 167.8 MB (proven footprint).  Lifetimes:
    //   slot0: Xk -> P-low          (Xk dead after k-proj)
    //   slot1: wh (6 MB) -> P-high  (wh dead after k-proj)
    //   slot2: Xv -> q              (Xv dead after v-proj; q written by q-proj)
    //   slot3: Xq -> k              (Xq dead after q-proj; k written by k-proj)
    //   slot4: vT                   (written directly by v-proj TRANSC epilogue)
    // Order: casts; v-proj; q-proj; k-proj; S-GEMM (P over slot0|slot1);
    //        softmax; PV.  All write-before-read, audited.
    const long long SH = (long long)8 * 2048 * 1024;
    f16* slot0 = (f16*)d_ws;
    f16* slot1 = slot0 + SH;
    f16* slot2 = slot0 + 2 * SH;
    f16* slot3 = slot0 + 3 * SH;
    f16* slot4 = slot0 + 4 * SH;
    f16* wh    = slot1;
    f16* Pb    = slot0;            // 8*2048*2048 f16 = 2*SH (slot0 + slot1)

    const int n16x = (int)(SH / 16);
    const int n16w = 1024 * 1024 / 16;
    const long long zero = 0;
    const long long M1 = 1024 * 1024;

    // 0) W -> f16 (into slot1)
    cast3_kernel<<<dim3(64, 1, 3), 256, 0, stream>>>(Wq, Wk, Wv, wh, wh + M1, wh + 2 * M1, n16w);
    // 1) X -> f16: Xq -> slot3, Xk -> slot0, Xv -> slot2
    cast3_kernel<<<dim3(1024, 1, 3), 256, 0, stream>>>(query, keyi, value, slot3, slot0, slot2, n16x);
    // 2) v-proj with fused transpose: vT -> slot4  (M=16384 N=1024 K=1024, gx=8)
    gemm_nt_k<1, 1><<<dim3(512, 1, 1), 512, 0, stream>>>(
        slot2, wh + 2 * M1, (void*)slot4, 1024, 1024, 1024, 2048, zero, zero, zero, 8);
    // 3) q-proj: q -> slot2 (Xv dead)
    gemm_nt_k<1, 0><<<dim3(512, 1, 1), 512, 0, stream>>>(
        slot3, wh, (void*)slot2, 1024, 1024, 1024, 1024, zero, zero, zero, 8);
    // 4) k-proj: k -> slot3 (Xq dead)
    gemm_nt_k<1, 0><<<dim3(512, 1, 1), 512, 0, stream>>>(
        slot0, wh + M1, (void*)slot3, 1024, 1024, 1024, 1024, zero, zero, zero, 8);
    // 5) S = q @ k^T per batch: M=N=2048 K=1024 -> grid 8*16=128 per z, gx=16
    //    (P overwrites slot0|slot1; Xk and wh dead)
    gemm_nt_k<1, 0><<<dim3(128, 1, 8), 512, 0, stream>>>(
        slot2, slot3, (void*)Pb, 1024, 1024, 1024, 2048,
        (long long)2048 * 1024, (long long)2048 * 1024, (long long)2048 * 2048, 16);
    // 6) P = masked softmax(S), in place
    softmax_kernel<<<dim3(16384), 256, 0, stream>>>(Pb, mask);
    // 7) context = P @ vT^T: M=2048 N=1024 K=2048 -> grid 8*8=64 per z, gx=8
    gemm_nt_k<0, 0><<<dim3(64, 1, 8), 512, 0, stream>>>(
        Pb, slot4, (void*)out, 2048, 2048, 2048, 1024,
        (long long)2048 * 2048, (long long)1024 * 2048, (long long)2048 * 1024, 8);
}